// Round 3
// baseline (915.477 us; speedup 1.0000x reference)
//
#include <hip/hip_runtime.h>
#include <hip/hip_bf16.h>

// PolicyNet inference: 4 pyramid levels, each: GN(8g)->ReLU->Conv1x1(256->256)
// ->GN->ReLU->Conv1x1(256->1); concat logits [8,21760]; top-100 indices.
// d_out is FLOAT32: [8*100 sample_ids as floats][8*21760 logits as f32].
//
// ws layout (floats), ~0.3 MB:
//   ab1 @ 0     : 16384   (alpha 8192 | beta 8192)
//   ab2 @ 16384 : 16384
//   U   @ 32768 : 43520   union{part1(10880), part2(43520), cval(6400)+cidx(6400)}

#define B_ 8
#define C_ 256
#define G_ 8
#define P_ 21760
#define EPSV 1e-5f
#define WS_STRIDE 260   // padded LDS stride for W tile (260*4 % 16 == 0)

__device__ __constant__ int kL[4]   = {16384, 4096, 1024, 256};
__device__ __constant__ int kOFF[4] = {0, 16384, 20480, 21504};

__device__ __forceinline__ bool better(float v1, int i1, float v2, int i2) {
    return (v1 > v2) || (v1 == v2 && i1 < i2);
}

// ---------------- GN1 partial stats: per (b, 256-pixel chunk, group) ----------------
__global__ __launch_bounds__(256) void k_stats1(const float* __restrict__ x0,
                                                const float* __restrict__ x1,
                                                const float* __restrict__ x2,
                                                const float* __restrict__ x3,
                                                float* __restrict__ part1) {
    int chunk = blockIdx.x, b = blockIdx.y, t = threadIdx.x;
    int lvl = chunk < 64 ? 0 : (chunk < 80 ? 1 : (chunk < 84 ? 2 : 3));
    const float* xp = lvl == 0 ? x0 : lvl == 1 ? x1 : lvl == 2 ? x2 : x3;
    int Ll = kL[lvl];
    int l = chunk * 256 - kOFF[lvl] + t;
    __shared__ float red[8];
    for (int g = 0; g < 8; ++g) {
        float s = 0.f, q = 0.f;
        for (int cc = 0; cc < 32; ++cc) {
            int c = g * 32 + cc;
            float v = xp[(b * 256 + c) * Ll + l];
            s += v; q += v * v;
        }
        for (int off = 32; off; off >>= 1) {
            s += __shfl_down(s, off, 64);
            q += __shfl_down(q, off, 64);
        }
        if ((t & 63) == 0) { red[t >> 6] = s; red[4 + (t >> 6)] = q; }
        __syncthreads();
        if (t == 0) {
            part1[((b * 85 + chunk) * 8 + g) * 2]     = red[0] + red[1] + red[2] + red[3];
            part1[((b * 85 + chunk) * 8 + g) * 2 + 1] = red[4] + red[5] + red[6] + red[7];
        }
        __syncthreads();
    }
}

// ---------------- finalize stats -> per-(b,lvl,c) affine alpha/beta ----------------
__global__ __launch_bounds__(256) void k_finalize(const float* __restrict__ part, int div,
                                                  const float* __restrict__ gsc,
                                                  const float* __restrict__ gbi,
                                                  float* __restrict__ ab) {
    int t = threadIdx.x;
    int b = t >> 5, lvl = (t >> 3) & 3, g = t & 7;
    int start = kOFF[lvl] / div, cnt = kL[lvl] / div, nch = P_ / div;
    float s = 0.f, q = 0.f;
    for (int m = 0; m < cnt; ++m) {
        const float* p = part + ((b * nch + start + m) * 8 + g) * 2;
        s += p[0]; q += p[1];
    }
    float N = 32.f * (float)kL[lvl];
    float mean = s / N;
    float var = q / N - mean * mean;
    float inv = rsqrtf(var + EPSV);
    for (int cc = 0; cc < 32; ++cc) {
        int c = g * 32 + cc;
        float a = inv * gsc[c];
        ab[(b * 4 + lvl) * 256 + c] = a;
        ab[8192 + (b * 4 + lvl) * 256 + c] = gbi[c] - mean * a;
    }
}

// ---------------- GEMM: Y[b,o,p] = b1[o] + sum_c W1[o,c]*relu(a1*x+be1) ----------------
// Tile: full M=256 (o), N=64 pixels, K chunks of 32. 256 thr, 8x8 micro-tile.
// MODE 0: GN2 partial stats only. MODE 2: fused GN2+W2 -> f32 logits at out+800.
template <int MODE>
__global__ __launch_bounds__(256) void k_gemm(
    const float* __restrict__ x0, const float* __restrict__ x1,
    const float* __restrict__ x2, const float* __restrict__ x3,
    const float* __restrict__ W1, const float* __restrict__ ab1,
    const float* __restrict__ b1, float* __restrict__ part2,
    const float* __restrict__ ab2, const float* __restrict__ W2,
    const float* __restrict__ b2, float* __restrict__ outF) {
    __shared__ float lds[32 * WS_STRIDE + 2048];   // Ws[32][260] @0, Xs[32][64] after
    float* Wsm = lds;
    float* Xsm = lds + 32 * WS_STRIDE;

    int tile = blockIdx.x, b = blockIdx.y, t = threadIdx.x;
    int lvl = tile < 256 ? 0 : (tile < 320 ? 1 : (tile < 336 ? 2 : 3));
    const float* xp = lvl == 0 ? x0 : lvl == 1 ? x1 : lvl == 2 ? x2 : x3;
    int Ll = kL[lvl];
    int l0 = tile * 64 - kOFF[lvl];
    int to = t >> 3, tl = t & 7;

    const float* a1p  = ab1 + (b * 4 + lvl) * 256;
    const float* be1p = a1p + 8192;

    float acc[64];
#pragma unroll
    for (int i = 0; i < 64; ++i) acc[i] = 0.f;

    for (int kk = 0; kk < 8; ++kk) {
        // stage Xs = relu(a1*x + be1): 32 rows x 64 px -> 2 float4/thread
#pragma unroll
        for (int s = 0; s < 2; ++s) {
            int f = t + s * 256;
            int row = f >> 4, c4 = (f & 15) * 4;
            int c = kk * 32 + row;
            float4 v = *reinterpret_cast<const float4*>(xp + (b * 256 + c) * Ll + l0 + c4);
            float a = a1p[c], be = be1p[c];
            float4 h;
            h.x = fmaxf(fmaf(a, v.x, be), 0.f);
            h.y = fmaxf(fmaf(a, v.y, be), 0.f);
            h.z = fmaxf(fmaf(a, v.z, be), 0.f);
            h.w = fmaxf(fmaf(a, v.w, be), 0.f);
            *reinterpret_cast<float4*>(&Xsm[row * 64 + c4]) = h;
        }
        // stage Ws[cc][o] = W1[o][kk*32+cc]: read float4 along c, write transposed
#pragma unroll
        for (int s = 0; s < 8; ++s) {
            int o = s * 32 + (t >> 3);
            int c4 = (t & 7) * 4;
            float4 wv = *reinterpret_cast<const float4*>(W1 + o * 256 + kk * 32 + c4);
            Wsm[(c4 + 0) * WS_STRIDE + o] = wv.x;
            Wsm[(c4 + 1) * WS_STRIDE + o] = wv.y;
            Wsm[(c4 + 2) * WS_STRIDE + o] = wv.z;
            Wsm[(c4 + 3) * WS_STRIDE + o] = wv.w;
        }
        __syncthreads();
#pragma unroll 4
        for (int k = 0; k < 32; ++k) {
            const float4 w0 = *reinterpret_cast<const float4*>(&Wsm[k * WS_STRIDE + to * 8]);
            const float4 w1 = *reinterpret_cast<const float4*>(&Wsm[k * WS_STRIDE + to * 8 + 4]);
            const float4 p0 = *reinterpret_cast<const float4*>(&Xsm[k * 64 + tl * 8]);
            const float4 p1 = *reinterpret_cast<const float4*>(&Xsm[k * 64 + tl * 8 + 4]);
            const float wa[8] = {w0.x, w0.y, w0.z, w0.w, w1.x, w1.y, w1.z, w1.w};
            const float pa[8] = {p0.x, p0.y, p0.z, p0.w, p1.x, p1.y, p1.z, p1.w};
#pragma unroll
            for (int i = 0; i < 8; ++i)
#pragma unroll
                for (int j = 0; j < 8; ++j)
                    acc[i * 8 + j] = fmaf(wa[i], pa[j], acc[i * 8 + j]);
        }
        __syncthreads();
    }

    float b1v[8];
#pragma unroll
    for (int i = 0; i < 8; ++i) b1v[i] = b1[to * 8 + i];

    if (MODE == 0) {
        float s = 0.f, q = 0.f;
#pragma unroll
        for (int i = 0; i < 8; ++i)
#pragma unroll
            for (int j = 0; j < 8; ++j) {
                float yv = acc[i * 8 + j] + b1v[i];
                s += yv; q += yv * yv;
            }
        float* rs = lds;          // reuse (post-barrier)
        float* rq = lds + 256;
        rs[t] = s; rq[t] = q;
        __syncthreads();
        if (t < 8) {  // threads t*32..t*32+31 all belong to o-group t
            float S = 0.f, Q = 0.f;
            for (int m = 0; m < 32; ++m) { S += rs[t * 32 + m]; Q += rq[t * 32 + m]; }
            part2[((b * 340 + tile) * 8 + t) * 2]     = S;
            part2[((b * 340 + tile) * 8 + t) * 2 + 1] = Q;
        }
    } else {  // MODE 2: fused GN2 -> ReLU -> W2 dot
        const float* a2p  = ab2 + (b * 4 + lvl) * 256;
        const float* be2p = a2p + 8192;
        float sj[8];
#pragma unroll
        for (int j = 0; j < 8; ++j) sj[j] = 0.f;
#pragma unroll
        for (int i = 0; i < 8; ++i) {
            int o = to * 8 + i;
            float a2 = a2p[o], be2 = be2p[o], w2 = W2[o];
#pragma unroll
            for (int j = 0; j < 8; ++j) {
                float h = fmaxf(fmaf(a2, acc[i * 8 + j] + b1v[i], be2), 0.f);
                sj[j] = fmaf(w2, h, sj[j]);
            }
        }
        float* partl = lds;  // [32][65] padded, reuse post-barrier
#pragma unroll
        for (int j = 0; j < 8; ++j) partl[to * 65 + tl * 8 + j] = sj[j];
        __syncthreads();
        if (t < 64) {
            float lg = b2[0];
            for (int to2 = 0; to2 < 32; ++to2) lg += partl[to2 * 65 + t];
            int p = tile * 64 + t;
            outF[800 + b * P_ + p] = lg;   // f32 logits live in d_out
        }
    }
}

// ---------------- top-k stage 1: per (b, segment of 2720) top-100 ----------------
__global__ __launch_bounds__(256) void k_topk_seg(const float* __restrict__ outF,
                                                  float* __restrict__ cval,
                                                  int* __restrict__ cidx) {
    int bid = blockIdx.x;
    int b = bid >> 3, s = bid & 7, t = threadIdx.x;
    __shared__ float vals[2720];
    __shared__ float wv[4];
    __shared__ int   wi[4];
    __shared__ int   bi_s;
    const float* src = outF + 800 + b * P_ + s * 2720;
    for (int m = 0; m < 11; ++m) {
        int l = t + m * 256;
        if (l < 2720) vals[l] = src[l];
    }
    __syncthreads();
    float cv = -__builtin_inff(); int ci = 0x7fffffff;
    for (int m = 0; m < 11; ++m) {
        int l = t + m * 256;
        if (l < 2720) { float v = vals[l]; if (better(v, l, cv, ci)) { cv = v; ci = l; } }
    }
    for (int r = 0; r < 100; ++r) {
        float v = cv; int i = ci;
        for (int off = 32; off; off >>= 1) {
            float ov = __shfl_xor(v, off, 64);
            int   oi = __shfl_xor(i, off, 64);
            if (better(ov, oi, v, i)) { v = ov; i = oi; }
        }
        if ((t & 63) == 0) { wv[t >> 6] = v; wi[t >> 6] = i; }
        __syncthreads();
        if (t == 0) {
            float bv = wv[0]; int bi = wi[0];
            for (int w = 1; w < 4; ++w)
                if (better(wv[w], wi[w], bv, bi)) { bv = wv[w]; bi = wi[w]; }
            bi_s = bi;
            cval[bid * 100 + r] = bv;
            cidx[bid * 100 + r] = s * 2720 + bi;
        }
        __syncthreads();
        int bi = bi_s;
        if ((bi & 255) == t) {
            vals[bi] = -__builtin_inff();
            cv = -__builtin_inff(); ci = 0x7fffffff;
            for (int m = 0; m < 11; ++m) {
                int l = t + m * 256;
                if (l < 2720) { float v = vals[l]; if (better(v, l, cv, ci)) { cv = v; ci = l; } }
            }
        }
        __syncthreads();
    }
}

// ---------------- top-k stage 2: merge 8x100 per batch -> 100 ids (as f32) ----------------
// LDS position order (seg-major, rank-minor) == global index tie-break order.
__global__ __launch_bounds__(256) void k_topk_merge(const float* __restrict__ cval,
                                                    const int* __restrict__ cidx,
                                                    float* __restrict__ outF) {
    int b = blockIdx.x, t = threadIdx.x;
    __shared__ float vals[800];
    __shared__ int   gidx[800];
    __shared__ float wv[4];
    __shared__ int   wi[4];
    __shared__ int   bi_s;
    for (int m = 0; m < 4; ++m) {
        int l = t + m * 256;
        if (l < 800) { vals[l] = cval[b * 800 + l]; gidx[l] = cidx[b * 800 + l]; }
    }
    __syncthreads();
    float cv = -__builtin_inff(); int ci = 0x7fffffff;
    for (int m = 0; m < 4; ++m) {
        int l = t + m * 256;
        if (l < 800) { float v = vals[l]; if (better(v, l, cv, ci)) { cv = v; ci = l; } }
    }
    for (int r = 0; r < 100; ++r) {
        float v = cv; int i = ci;
        for (int off = 32; off; off >>= 1) {
            float ov = __shfl_xor(v, off, 64);
            int   oi = __shfl_xor(i, off, 64);
            if (better(ov, oi, v, i)) { v = ov; i = oi; }
        }
        if ((t & 63) == 0) { wv[t >> 6] = v; wi[t >> 6] = i; }
        __syncthreads();
        if (t == 0) {
            float bv = wv[0]; int bi = wi[0];
            for (int w = 1; w < 4; ++w)
                if (better(wv[w], wi[w], bv, bi)) { bv = wv[w]; bi = wi[w]; }
            bi_s = bi;
            outF[b * 100 + r] = (float)gidx[bi];
        }
        __syncthreads();
        int bi = bi_s;
        if ((bi & 255) == t) {
            vals[bi] = -__builtin_inff();
            cv = -__builtin_inff(); ci = 0x7fffffff;
            for (int m = 0; m < 4; ++m) {
                int l = t + m * 256;
                if (l < 800) { float v = vals[l]; if (better(v, l, cv, ci)) { cv = v; ci = l; } }
            }
        }
        __syncthreads();
    }
}

extern "C" void kernel_launch(void* const* d_in, const int* in_sizes, int n_in,
                              void* d_out, int out_size, void* d_ws, size_t ws_size,
                              hipStream_t stream) {
    const float* x0  = (const float*)d_in[0];
    const float* x1  = (const float*)d_in[1];
    const float* x2  = (const float*)d_in[2];
    const float* x3  = (const float*)d_in[3];
    const float* g1s = (const float*)d_in[4];
    const float* g1b = (const float*)d_in[5];
    const float* W1  = (const float*)d_in[6];
    const float* b1  = (const float*)d_in[7];
    const float* g2s = (const float*)d_in[8];
    const float* g2b = (const float*)d_in[9];
    const float* W2  = (const float*)d_in[10];
    const float* b2  = (const float*)d_in[11];
    float* outF = (float*)d_out;             // f32 output buffer
    float* ws = (float*)d_ws;

    // ws layout (floats) — 76288 floats (~0.3 MB)
    float* ab1   = ws;                    // 16384
    float* ab2   = ws + 16384;            // 16384
    float* U     = ws + 32768;            // 43520 shared region
    float* part1 = U;                     // 10880 (dead after finalize1)
    float* part2 = U;                     // 43520 (dead after finalize2)
    float* cval  = U;                     // 6400  (live during topk)
    int*   cidx  = (int*)(U + 6400);      // 6400

    k_stats1<<<dim3(85, 8), dim3(256), 0, stream>>>(x0, x1, x2, x3, part1);
    k_finalize<<<dim3(1), dim3(256), 0, stream>>>(part1, 256, g1s, g1b, ab1);
    k_gemm<0><<<dim3(340, 8), dim3(256), 0, stream>>>(x0, x1, x2, x3, W1, ab1, b1,
                                                      part2, ab2, W2, b2, outF);
    k_finalize<<<dim3(1), dim3(256), 0, stream>>>(part2, 64, g2s, g2b, ab2);
    k_gemm<2><<<dim3(340, 8), dim3(256), 0, stream>>>(x0, x1, x2, x3, W1, ab1, b1,
                                                      part2, ab2, W2, b2, outF);
    k_topk_seg<<<dim3(64), dim3(256), 0, stream>>>(outF, cval, cidx);
    k_topk_merge<<<dim3(8), dim3(256), 0, stream>>>(cval, cidx, outF);
}

// Round 4
// 553.244 us; speedup vs baseline: 1.6547x; 1.6547x over previous
//
#include <hip/hip_runtime.h>
#include <hip/hip_bf16.h>

// PolicyNet inference: 4 pyramid levels, each: GN(8g)->ReLU->Conv1x1(256->256)
// ->GN->ReLU->Conv1x1(256->1); concat logits [8,21760]; top-100 indices.
// d_out is FLOAT32: [8*100 sample_ids as floats][8*21760 logits as f32].
//
// GEMM runs on MFMA (16x16x32 bf16) with hi/lo split for f32-like accuracy:
//   W*X ~= Whi*Xhi + Whi*Xlo + Wlo*Xhi   (error ~2^-16 relative per product)

#define B_ 8
#define C_ 256
#define G_ 8
#define P_ 21760
#define EPSV 1e-5f
#define XS_STRIDE 72   // bf16 elems per pixel row in LDS (144B, 16B-aligned)

typedef __attribute__((ext_vector_type(4))) float floatx4;
typedef __attribute__((ext_vector_type(8))) __bf16 bf16x8;

__device__ __constant__ int kL[4]   = {16384, 4096, 1024, 256};
__device__ __constant__ int kOFF[4] = {0, 16384, 20480, 21504};

__device__ __forceinline__ bool better(float v1, int i1, float v2, int i2) {
    return (v1 > v2) || (v1 == v2 && i1 < i2);
}

__device__ __forceinline__ void bf16split(float v, ushort& hi, ushort& lo) {
    __hip_bfloat16 h = __float2bfloat16(v);
    float hf = __bfloat162float(h);
    __hip_bfloat16 l = __float2bfloat16(v - hf);
    hi = *reinterpret_cast<ushort*>(&h);
    lo = *reinterpret_cast<ushort*>(&l);
}

// ---------------- W split: Whi/Wlo[o][c] bf16 ----------------
__global__ __launch_bounds__(256) void k_wsplit(const float* __restrict__ W1,
                                                ushort* __restrict__ Whi,
                                                ushort* __restrict__ Wlo) {
    int i = blockIdx.x * 256 + threadIdx.x;   // 256 blocks -> 65536
    ushort h, l;
    bf16split(W1[i], h, l);
    Whi[i] = h; Wlo[i] = l;
}

// ---------------- GN1 partial stats (float4 loads) ----------------
__global__ __launch_bounds__(256) void k_stats1(const float* __restrict__ x0,
                                                const float* __restrict__ x1,
                                                const float* __restrict__ x2,
                                                const float* __restrict__ x3,
                                                float* __restrict__ part1) {
    int chunk = blockIdx.x, b = blockIdx.y, t = threadIdx.x;
    int lvl = chunk < 64 ? 0 : (chunk < 80 ? 1 : (chunk < 84 ? 2 : 3));
    const float* xp = lvl == 0 ? x0 : lvl == 1 ? x1 : lvl == 2 ? x2 : x3;
    int Ll = kL[lvl];
    int w = t >> 6, lane = t & 63;
    int l = chunk * 256 - kOFF[lvl] + lane * 4;
    __shared__ float red[8];
    for (int g = 0; g < 8; ++g) {
        float s = 0.f, q = 0.f;
#pragma unroll
        for (int it = 0; it < 8; ++it) {
            int c = g * 32 + w * 8 + it;
            floatx4 v = *reinterpret_cast<const floatx4*>(xp + (b * 256 + c) * Ll + l);
            s += v.x + v.y + v.z + v.w;
            q += v.x * v.x + v.y * v.y + v.z * v.z + v.w * v.w;
        }
        for (int off = 32; off; off >>= 1) {
            s += __shfl_xor(s, off, 64);
            q += __shfl_xor(q, off, 64);
        }
        if (lane == 0) { red[w] = s; red[4 + w] = q; }
        __syncthreads();
        if (t == 0) {
            part1[((b * 85 + chunk) * 8 + g) * 2]     = red[0] + red[1] + red[2] + red[3];
            part1[((b * 85 + chunk) * 8 + g) * 2 + 1] = red[4] + red[5] + red[6] + red[7];
        }
        __syncthreads();
    }
}

// ---------------- finalize stats -> per-(b,lvl,c) affine alpha/beta ----------------
__global__ __launch_bounds__(256) void k_finalize(const float* __restrict__ part, int div,
                                                  const float* __restrict__ gsc,
                                                  const float* __restrict__ gbi,
                                                  float* __restrict__ ab) {
    int t = threadIdx.x;
    int b = t >> 5, lvl = (t >> 3) & 3, g = t & 7;
    int start = kOFF[lvl] / div, cnt = kL[lvl] / div, nch = P_ / div;
    float s = 0.f, q = 0.f;
    for (int m = 0; m < cnt; ++m) {
        const float* p = part + ((b * nch + start + m) * 8 + g) * 2;
        s += p[0]; q += p[1];
    }
    float N = 32.f * (float)kL[lvl];
    float mean = s / N;
    float var = q / N - mean * mean;
    float inv = rsqrtf(var + EPSV);
    for (int cc = 0; cc < 32; ++cc) {
        int c = g * 32 + cc;
        float a = inv * gsc[c];
        ab[(b * 4 + lvl) * 256 + c] = a;
        ab[8192 + (b * 4 + lvl) * 256 + c] = gbi[c] - mean * a;
    }
}

// ---------------- MFMA GEMM: Y[b,o,p] = b1[o] + sum_c W1[o,c]*relu(a1*x+be1) ----------------
// Block: 256 thr = 4 waves. Tile M=256 (o, 64/wave), N=64 (pixels), K=256 in 8 chunks.
// Per chunk: X tile transposed+split into LDS [p][c] bf16; W frags direct from global.
// MFMA 16x16x32 bf16: A lane l holds A[l&15][8*(l>>4)+j]; B: B[8*(l>>4)+j][l&15];
// D: row(m)=4*(l>>4)+reg, col(n)=l&15  [m89-verified].
// MODE 0: GN2 partial stats. MODE 2: fused GN2+W2 -> f32 logits at outF+800.
template <int MODE>
__global__ __launch_bounds__(256, 2) void k_gemm(
    const float* __restrict__ x0, const float* __restrict__ x1,
    const float* __restrict__ x2, const float* __restrict__ x3,
    const ushort* __restrict__ Whi, const ushort* __restrict__ Wlo,
    const float* __restrict__ ab1, const float* __restrict__ b1,
    float* __restrict__ part2, const float* __restrict__ ab2,
    const float* __restrict__ W2, const float* __restrict__ b2,
    float* __restrict__ outF) {
    __shared__ ushort Xs[2 * 64 * XS_STRIDE];   // hi @0, lo @4608
    ushort* XsHi = Xs;
    ushort* XsLo = Xs + 64 * XS_STRIDE;

    int tile = blockIdx.x, b = blockIdx.y, t = threadIdx.x;
    int wv = t >> 6, lane = t & 63, lr = lane & 15, kg = lane >> 4;
    int lvl = tile < 256 ? 0 : (tile < 320 ? 1 : (tile < 336 ? 2 : 3));
    const float* xp = lvl == 0 ? x0 : lvl == 1 ? x1 : lvl == 2 ? x2 : x3;
    int Ll = kL[lvl];
    int l0 = tile * 64 - kOFF[lvl];
    int ob = wv * 64;

    const float* a1p  = ab1 + (b * 4 + lvl) * 256;
    const float* be1p = a1p + 8192;

    floatx4 acc[4][4];
#pragma unroll
    for (int mi = 0; mi < 4; ++mi)
#pragma unroll
        for (int ni = 0; ni < 4; ++ni) acc[mi][ni] = (floatx4){0.f, 0.f, 0.f, 0.f};

    for (int kk = 0; kk < 8; ++kk) {
        // ---- stage X chunk: 32 c x 64 p, relu(a1*x+be1), split hi/lo, transpose ----
#pragma unroll
        for (int s = 0; s < 2; ++s) {
            int f = t + s * 256;
            int cl = f >> 4;             // 0..31
            int p4 = (f & 15) * 4;       // 0..60
            int c = kk * 32 + cl;
            floatx4 v = *reinterpret_cast<const floatx4*>(xp + (b * 256 + c) * Ll + l0 + p4);
            float a = a1p[c], be = be1p[c];
            float h0 = fmaxf(fmaf(a, v.x, be), 0.f);
            float h1 = fmaxf(fmaf(a, v.y, be), 0.f);
            float h2 = fmaxf(fmaf(a, v.z, be), 0.f);
            float h3 = fmaxf(fmaf(a, v.w, be), 0.f);
            ushort hi, lo;
            bf16split(h0, hi, lo); XsHi[(p4 + 0) * XS_STRIDE + cl] = hi; XsLo[(p4 + 0) * XS_STRIDE + cl] = lo;
            bf16split(h1, hi, lo); XsHi[(p4 + 1) * XS_STRIDE + cl] = hi; XsLo[(p4 + 1) * XS_STRIDE + cl] = lo;
            bf16split(h2, hi, lo); XsHi[(p4 + 2) * XS_STRIDE + cl] = hi; XsLo[(p4 + 2) * XS_STRIDE + cl] = lo;
            bf16split(h3, hi, lo); XsHi[(p4 + 3) * XS_STRIDE + cl] = hi; XsLo[(p4 + 3) * XS_STRIDE + cl] = lo;
        }
        __syncthreads();

        // ---- fragments ----
        int ko = kk * 32 + 8 * kg;
        bf16x8 ah[4], al[4], bh[4], bl[4];
#pragma unroll
        for (int mi = 0; mi < 4; ++mi) {
            int o = ob + mi * 16 + lr;
            ah[mi] = *reinterpret_cast<const bf16x8*>(Whi + o * 256 + ko);
            al[mi] = *reinterpret_cast<const bf16x8*>(Wlo + o * 256 + ko);
        }
#pragma unroll
        for (int ni = 0; ni < 4; ++ni) {
            int p = ni * 16 + lr;
            bh[ni] = *reinterpret_cast<const bf16x8*>(XsHi + p * XS_STRIDE + 8 * kg);
            bl[ni] = *reinterpret_cast<const bf16x8*>(XsLo + p * XS_STRIDE + 8 * kg);
        }
#pragma unroll
        for (int mi = 0; mi < 4; ++mi)
#pragma unroll
            for (int ni = 0; ni < 4; ++ni) {
                acc[mi][ni] = __builtin_amdgcn_mfma_f32_16x16x32_bf16(ah[mi], bh[ni], acc[mi][ni], 0, 0, 0);
                acc[mi][ni] = __builtin_amdgcn_mfma_f32_16x16x32_bf16(ah[mi], bl[ni], acc[mi][ni], 0, 0, 0);
                acc[mi][ni] = __builtin_amdgcn_mfma_f32_16x16x32_bf16(al[mi], bh[ni], acc[mi][ni], 0, 0, 0);
            }
        __syncthreads();
    }

    // per-thread o rows: o = ob + mi*16 + 4*kg + r
    floatx4 b1f[4];
#pragma unroll
    for (int mi = 0; mi < 4; ++mi)
        b1f[mi] = *reinterpret_cast<const floatx4*>(b1 + ob + mi * 16 + 4 * kg);

    if (MODE == 0) {
        float sA = 0.f, qA = 0.f, sB = 0.f, qB = 0.f;
#pragma unroll
        for (int mi = 0; mi < 4; ++mi)
#pragma unroll
            for (int ni = 0; ni < 4; ++ni)
#pragma unroll
                for (int r = 0; r < 4; ++r) {
                    float yv = acc[mi][ni][r] + b1f[mi][r];
                    if (mi < 2) { sA += yv; qA += yv * yv; }
                    else        { sB += yv; qB += yv * yv; }
                }
        for (int off = 32; off; off >>= 1) {
            sA += __shfl_xor(sA, off, 64);
            qA += __shfl_xor(qA, off, 64);
            sB += __shfl_xor(sB, off, 64);
            qB += __shfl_xor(qB, off, 64);
        }
        if (lane == 0) {
            int base = (b * 340 + tile) * 8;
            part2[(base + 2 * wv) * 2]         = sA;
            part2[(base + 2 * wv) * 2 + 1]     = qA;
            part2[(base + 2 * wv + 1) * 2]     = sB;
            part2[(base + 2 * wv + 1) * 2 + 1] = qB;
        }
    } else {  // MODE 2: fused GN2 -> ReLU -> W2 dot
        const float* a2p  = ab2 + (b * 4 + lvl) * 256;
        const float* be2p = a2p + 8192;
        float sj[4] = {0.f, 0.f, 0.f, 0.f};
#pragma unroll
        for (int mi = 0; mi < 4; ++mi) {
            int o4 = ob + mi * 16 + 4 * kg;
            floatx4 a2f  = *reinterpret_cast<const floatx4*>(a2p + o4);
            floatx4 be2f = *reinterpret_cast<const floatx4*>(be2p + o4);
            floatx4 w2f  = *reinterpret_cast<const floatx4*>(W2 + o4);
#pragma unroll
            for (int r = 0; r < 4; ++r) {
                float a2 = a2f[r], be2 = be2f[r], w2 = w2f[r], bb = b1f[mi][r];
#pragma unroll
                for (int ni = 0; ni < 4; ++ni) {
                    float h = fmaxf(fmaf(a2, acc[mi][ni][r] + bb, be2), 0.f);
                    sj[ni] = fmaf(w2, h, sj[ni]);
                }
            }
        }
        float* red = reinterpret_cast<float*>(Xs);   // 1024 floats, post-barrier reuse
#pragma unroll
        for (int ni = 0; ni < 4; ++ni)
            red[(wv * 4 + kg) * 64 + ni * 16 + lr] = sj[ni];
        __syncthreads();
        if (t < 64) {
            float lg = b2[0];
#pragma unroll
            for (int m = 0; m < 16; ++m) lg += red[m * 64 + t];
            outF[800 + b * P_ + tile * 64 + t] = lg;
        }
    }
}

// ---------------- top-k stage 1: per (b, segment of 2720) top-100 ----------------
__global__ __launch_bounds__(256) void k_topk_seg(const float* __restrict__ outF,
                                                  float* __restrict__ cval,
                                                  int* __restrict__ cidx) {
    int bid = blockIdx.x;
    int b = bid >> 3, s = bid & 7, t = threadIdx.x;
    __shared__ float vals[2720];
    __shared__ float wv[4];
    __shared__ int   wi[4];
    __shared__ int   bi_s;
    const float* src = outF + 800 + b * P_ + s * 2720;
    for (int m = 0; m < 11; ++m) {
        int l = t + m * 256;
        if (l < 2720) vals[l] = src[l];
    }
    __syncthreads();
    float cv = -__builtin_inff(); int ci = 0x7fffffff;
    for (int m = 0; m < 11; ++m) {
        int l = t + m * 256;
        if (l < 2720) { float v = vals[l]; if (better(v, l, cv, ci)) { cv = v; ci = l; } }
    }
    for (int r = 0; r < 100; ++r) {
        float v = cv; int i = ci;
        for (int off = 32; off; off >>= 1) {
            float ov = __shfl_xor(v, off, 64);
            int   oi = __shfl_xor(i, off, 64);
            if (better(ov, oi, v, i)) { v = ov; i = oi; }
        }
        if ((t & 63) == 0) { wv[t >> 6] = v; wi[t >> 6] = i; }
        __syncthreads();
        if (t == 0) {
            float bv = wv[0]; int bi = wi[0];
            for (int w = 1; w < 4; ++w)
                if (better(wv[w], wi[w], bv, bi)) { bv = wv[w]; bi = wi[w]; }
            bi_s = bi;
            cval[bid * 100 + r] = bv;
            cidx[bid * 100 + r] = s * 2720 + bi;
        }
        __syncthreads();
        int bi = bi_s;
        if ((bi & 255) == t) {
            vals[bi] = -__builtin_inff();
            cv = -__builtin_inff(); ci = 0x7fffffff;
            for (int m = 0; m < 11; ++m) {
                int l = t + m * 256;
                if (l < 2720) { float v = vals[l]; if (better(v, l, cv, ci)) { cv = v; ci = l; } }
            }
        }
        __syncthreads();
    }
}

// ---------------- top-k stage 2: merge 8x100 per batch -> 100 ids (as f32) ----------------
__global__ __launch_bounds__(256) void k_topk_merge(const float* __restrict__ cval,
                                                    const int* __restrict__ cidx,
                                                    float* __restrict__ outF) {
    int b = blockIdx.x, t = threadIdx.x;
    __shared__ float vals[800];
    __shared__ int   gidx[800];
    __shared__ float wv[4];
    __shared__ int   wi[4];
    __shared__ int   bi_s;
    for (int m = 0; m < 4; ++m) {
        int l = t + m * 256;
        if (l < 800) { vals[l] = cval[b * 800 + l]; gidx[l] = cidx[b * 800 + l]; }
    }
    __syncthreads();
    float cv = -__builtin_inff(); int ci = 0x7fffffff;
    for (int m = 0; m < 4; ++m) {
        int l = t + m * 256;
        if (l < 800) { float v = vals[l]; if (better(v, l, cv, ci)) { cv = v; ci = l; } }
    }
    for (int r = 0; r < 100; ++r) {
        float v = cv; int i = ci;
        for (int off = 32; off; off >>= 1) {
            float ov = __shfl_xor(v, off, 64);
            int   oi = __shfl_xor(i, off, 64);
            if (better(ov, oi, v, i)) { v = ov; i = oi; }
        }
        if ((t & 63) == 0) { wv[t >> 6] = v; wi[t >> 6] = i; }
        __syncthreads();
        if (t == 0) {
            float bv = wv[0]; int bi = wi[0];
            for (int w = 1; w < 4; ++w)
                if (better(wv[w], wi[w], bv, bi)) { bv = wv[w]; bi = wi[w]; }
            bi_s = bi;
            outF[b * 100 + r] = (float)gidx[bi];
        }
        __syncthreads();
        int bi = bi_s;
        if ((bi & 255) == t) {
            vals[bi] = -__builtin_inff();
            cv = -__builtin_inff(); ci = 0x7fffffff;
            for (int m = 0; m < 4; ++m) {
                int l = t + m * 256;
                if (l < 800) { float v = vals[l]; if (better(v, l, cv, ci)) { cv = v; ci = l; } }
            }
        }
        __syncthreads();
    }
}

extern "C" void kernel_launch(void* const* d_in, const int* in_sizes, int n_in,
                              void* d_out, int out_size, void* d_ws, size_t ws_size,
                              hipStream_t stream) {
    const float* x0  = (const float*)d_in[0];
    const float* x1  = (const float*)d_in[1];
    const float* x2  = (const float*)d_in[2];
    const float* x3  = (const float*)d_in[3];
    const float* g1s = (const float*)d_in[4];
    const float* g1b = (const float*)d_in[5];
    const float* W1  = (const float*)d_in[6];
    const float* b1  = (const float*)d_in[7];
    const float* g2s = (const float*)d_in[8];
    const float* g2b = (const float*)d_in[9];
    const float* W2  = (const float*)d_in[10];
    const float* b2  = (const float*)d_in[11];
    float* outF = (float*)d_out;
    float* ws = (float*)d_ws;

    // ws layout (floats) — 141824 floats (~0.57 MB)
    float*  ab1   = ws;                     // 16384
    float*  ab2   = ws + 16384;             // 16384
    float*  U     = ws + 32768;             // 43520 shared region
    float*  part1 = U;                      // 10880 (dead after finalize1)
    float*  part2 = U;                      // 43520 (dead after finalize2)
    float*  cval  = U;                      // 6400  (live during topk)
    int*    cidx  = (int*)(U + 6400);       // 6400
    ushort* Whi   = (ushort*)(ws + 76288);  // 65536 ushorts (32768 floats)
    ushort* Wlo   = (ushort*)(ws + 109056); // 65536 ushorts

    k_wsplit<<<dim3(256), dim3(256), 0, stream>>>(W1, Whi, Wlo);
    k_stats1<<<dim3(85, 8), dim3(256), 0, stream>>>(x0, x1, x2, x3, part1);
    k_finalize<<<dim3(1), dim3(256), 0, stream>>>(part1, 256, g1s, g1b, ab1);
    k_gemm<0><<<dim3(340, 8), dim3(256), 0, stream>>>(x0, x1, x2, x3, Whi, Wlo, ab1, b1,
                                                      part2, ab2, W2, b2, outF);
    k_finalize<<<dim3(1), dim3(256), 0, stream>>>(part2, 64, g2s, g2b, ab2);
    k_gemm<2><<<dim3(340, 8), dim3(256), 0, stream>>>(x0, x1, x2, x3, Whi, Wlo, ab1, b1,
                                                      part2, ab2, W2, b2, outF);
    k_topk_seg<<<dim3(64), dim3(256), 0, stream>>>(outF, cval, cidx);
    k_topk_merge<<<dim3(8), dim3(256), 0, stream>>>(cval, cidx, outF);
}

// Round 5
// 365.337 us; speedup vs baseline: 2.5058x; 1.5143x over previous
//
#include <hip/hip_runtime.h>
#include <hip/hip_bf16.h>

// PolicyNet inference: 4 pyramid levels, each: GN(8g)->ReLU->Conv1x1(256->256)
// ->GN->ReLU->Conv1x1(256->1); concat logits [8,21760]; top-100 indices.
// d_out is FLOAT32: [8*100 sample_ids as floats][8*21760 logits as f32].
//
// GEMM on MFMA (16x16x32 bf16) with hi/lo split: W*X ~= Whi*Xhi + Whi*Xlo + Wlo*Xhi.
// Top-k via exact radix-select (value, then index for ties) + 128-wide bitonic sort.

#define B_ 8
#define C_ 256
#define G_ 8
#define P_ 21760
#define EPSV 1e-5f
#define XS_STRIDE 72   // bf16 elems per pixel row in LDS (144B, 16B-aligned)

typedef __attribute__((ext_vector_type(4))) float floatx4;
typedef __attribute__((ext_vector_type(8))) __bf16 bf16x8;

__device__ __constant__ int kL[4]   = {16384, 4096, 1024, 256};
__device__ __constant__ int kOFF[4] = {0, 16384, 20480, 21504};

__device__ __forceinline__ void bf16split(float v, ushort& hi, ushort& lo) {
    __hip_bfloat16 h = __float2bfloat16(v);
    float hf = __bfloat162float(h);
    __hip_bfloat16 l = __float2bfloat16(v - hf);
    hi = *reinterpret_cast<ushort*>(&h);
    lo = *reinterpret_cast<ushort*>(&l);
}

// order-preserving f32 -> u32 (descending float order == descending uint order)
__device__ __forceinline__ unsigned fkey(float f) {
    unsigned u = __float_as_uint(f);
    if (u == 0x80000000u) u = 0u;                    // canonicalize -0 -> +0
    return (u & 0x80000000u) ? ~u : (u | 0x80000000u);
}

// ---------------- W split: Whi/Wlo[o][c] bf16 ----------------
__global__ __launch_bounds__(256) void k_wsplit(const float* __restrict__ W1,
                                                ushort* __restrict__ Whi,
                                                ushort* __restrict__ Wlo) {
    int i = blockIdx.x * 256 + threadIdx.x;
    ushort h, l;
    bf16split(W1[i], h, l);
    Whi[i] = h; Wlo[i] = l;
}

// ---------------- GN1 partial stats (float4 loads, single barrier) ----------------
__global__ __launch_bounds__(256) void k_stats1(const float* __restrict__ x0,
                                                const float* __restrict__ x1,
                                                const float* __restrict__ x2,
                                                const float* __restrict__ x3,
                                                float* __restrict__ part1) {
    int chunk = blockIdx.x, b = blockIdx.y, t = threadIdx.x;
    int lvl = chunk < 64 ? 0 : (chunk < 80 ? 1 : (chunk < 84 ? 2 : 3));
    const float* xp = lvl == 0 ? x0 : lvl == 1 ? x1 : lvl == 2 ? x2 : x3;
    int Ll = kL[lvl];
    int w = t >> 6, lane = t & 63;
    int l = chunk * 256 - kOFF[lvl] + lane * 4;
    __shared__ float redS[32], redQ[32];
    for (int g = 0; g < 8; ++g) {
        float s = 0.f, q = 0.f;
#pragma unroll
        for (int it = 0; it < 8; ++it) {
            int c = g * 32 + w * 8 + it;
            floatx4 v = *reinterpret_cast<const floatx4*>(xp + (b * 256 + c) * Ll + l);
            s += v.x + v.y + v.z + v.w;
            q += v.x * v.x + v.y * v.y + v.z * v.z + v.w * v.w;
        }
        for (int off = 32; off; off >>= 1) {
            s += __shfl_xor(s, off, 64);
            q += __shfl_xor(q, off, 64);
        }
        if (lane == 0) { redS[g * 4 + w] = s; redQ[g * 4 + w] = q; }
    }
    __syncthreads();
    if (t < 8) {
        float S = redS[t * 4] + redS[t * 4 + 1] + redS[t * 4 + 2] + redS[t * 4 + 3];
        float Q = redQ[t * 4] + redQ[t * 4 + 1] + redQ[t * 4 + 2] + redQ[t * 4 + 3];
        part1[((b * 85 + chunk) * 8 + t) * 2]     = S;
        part1[((b * 85 + chunk) * 8 + t) * 2 + 1] = Q;
    }
}

// ---------------- finalize stats -> per-(b,lvl,c) affine alpha/beta ----------------
__global__ __launch_bounds__(256) void k_finalize(const float* __restrict__ part, int div,
                                                  const float* __restrict__ gsc,
                                                  const float* __restrict__ gbi,
                                                  float* __restrict__ ab) {
    int t = threadIdx.x;
    int b = t >> 5, lvl = (t >> 3) & 3, g = t & 7;
    int start = kOFF[lvl] / div, cnt = kL[lvl] / div, nch = P_ / div;
    float s = 0.f, q = 0.f;
    for (int m = 0; m < cnt; ++m) {
        const float* p = part + ((b * nch + start + m) * 8 + g) * 2;
        s += p[0]; q += p[1];
    }
    float N = 32.f * (float)kL[lvl];
    float mean = s / N;
    float var = q / N - mean * mean;
    float inv = rsqrtf(var + EPSV);
    for (int cc = 0; cc < 32; ++cc) {
        int c = g * 32 + cc;
        float a = inv * gsc[c];
        ab[(b * 4 + lvl) * 256 + c] = a;
        ab[8192 + (b * 4 + lvl) * 256 + c] = gbi[c] - mean * a;
    }
}

// ---------------- MFMA GEMM (unchanged from passing round) ----------------
template <int MODE>
__global__ __launch_bounds__(256, 2) void k_gemm(
    const float* __restrict__ x0, const float* __restrict__ x1,
    const float* __restrict__ x2, const float* __restrict__ x3,
    const ushort* __restrict__ Whi, const ushort* __restrict__ Wlo,
    const float* __restrict__ ab1, const float* __restrict__ b1,
    float* __restrict__ part2, const float* __restrict__ ab2,
    const float* __restrict__ W2, const float* __restrict__ b2,
    float* __restrict__ outF) {
    __shared__ ushort Xs[2 * 64 * XS_STRIDE];   // hi @0, lo after
    ushort* XsHi = Xs;
    ushort* XsLo = Xs + 64 * XS_STRIDE;

    int tile = blockIdx.x, b = blockIdx.y, t = threadIdx.x;
    int wv = t >> 6, lane = t & 63, lr = lane & 15, kg = lane >> 4;
    int lvl = tile < 256 ? 0 : (tile < 320 ? 1 : (tile < 336 ? 2 : 3));
    const float* xp = lvl == 0 ? x0 : lvl == 1 ? x1 : lvl == 2 ? x2 : x3;
    int Ll = kL[lvl];
    int l0 = tile * 64 - kOFF[lvl];
    int ob = wv * 64;

    const float* a1p  = ab1 + (b * 4 + lvl) * 256;
    const float* be1p = a1p + 8192;

    floatx4 acc[4][4];
#pragma unroll
    for (int mi = 0; mi < 4; ++mi)
#pragma unroll
        for (int ni = 0; ni < 4; ++ni) acc[mi][ni] = (floatx4){0.f, 0.f, 0.f, 0.f};

    for (int kk = 0; kk < 8; ++kk) {
#pragma unroll
        for (int s = 0; s < 2; ++s) {
            int f = t + s * 256;
            int cl = f >> 4;
            int p4 = (f & 15) * 4;
            int c = kk * 32 + cl;
            floatx4 v = *reinterpret_cast<const floatx4*>(xp + (b * 256 + c) * Ll + l0 + p4);
            float a = a1p[c], be = be1p[c];
            float h0 = fmaxf(fmaf(a, v.x, be), 0.f);
            float h1 = fmaxf(fmaf(a, v.y, be), 0.f);
            float h2 = fmaxf(fmaf(a, v.z, be), 0.f);
            float h3 = fmaxf(fmaf(a, v.w, be), 0.f);
            ushort hi, lo;
            bf16split(h0, hi, lo); XsHi[(p4 + 0) * XS_STRIDE + cl] = hi; XsLo[(p4 + 0) * XS_STRIDE + cl] = lo;
            bf16split(h1, hi, lo); XsHi[(p4 + 1) * XS_STRIDE + cl] = hi; XsLo[(p4 + 1) * XS_STRIDE + cl] = lo;
            bf16split(h2, hi, lo); XsHi[(p4 + 2) * XS_STRIDE + cl] = hi; XsLo[(p4 + 2) * XS_STRIDE + cl] = lo;
            bf16split(h3, hi, lo); XsHi[(p4 + 3) * XS_STRIDE + cl] = hi; XsLo[(p4 + 3) * XS_STRIDE + cl] = lo;
        }
        __syncthreads();

        int ko = kk * 32 + 8 * kg;
        bf16x8 ah[4], al[4], bh[4], bl[4];
#pragma unroll
        for (int mi = 0; mi < 4; ++mi) {
            int o = ob + mi * 16 + lr;
            ah[mi] = *reinterpret_cast<const bf16x8*>(Whi + o * 256 + ko);
            al[mi] = *reinterpret_cast<const bf16x8*>(Wlo + o * 256 + ko);
        }
#pragma unroll
        for (int ni = 0; ni < 4; ++ni) {
            int p = ni * 16 + lr;
            bh[ni] = *reinterpret_cast<const bf16x8*>(XsHi + p * XS_STRIDE + 8 * kg);
            bl[ni] = *reinterpret_cast<const bf16x8*>(XsLo + p * XS_STRIDE + 8 * kg);
        }
#pragma unroll
        for (int mi = 0; mi < 4; ++mi)
#pragma unroll
            for (int ni = 0; ni < 4; ++ni) {
                acc[mi][ni] = __builtin_amdgcn_mfma_f32_16x16x32_bf16(ah[mi], bh[ni], acc[mi][ni], 0, 0, 0);
                acc[mi][ni] = __builtin_amdgcn_mfma_f32_16x16x32_bf16(ah[mi], bl[ni], acc[mi][ni], 0, 0, 0);
                acc[mi][ni] = __builtin_amdgcn_mfma_f32_16x16x32_bf16(al[mi], bh[ni], acc[mi][ni], 0, 0, 0);
            }
        __syncthreads();
    }

    floatx4 b1f[4];
#pragma unroll
    for (int mi = 0; mi < 4; ++mi)
        b1f[mi] = *reinterpret_cast<const floatx4*>(b1 + ob + mi * 16 + 4 * kg);

    if (MODE == 0) {
        float sA = 0.f, qA = 0.f, sB = 0.f, qB = 0.f;
#pragma unroll
        for (int mi = 0; mi < 4; ++mi)
#pragma unroll
            for (int ni = 0; ni < 4; ++ni)
#pragma unroll
                for (int r = 0; r < 4; ++r) {
                    float yv = acc[mi][ni][r] + b1f[mi][r];
                    if (mi < 2) { sA += yv; qA += yv * yv; }
                    else        { sB += yv; qB += yv * yv; }
                }
        for (int off = 32; off; off >>= 1) {
            sA += __shfl_xor(sA, off, 64);
            qA += __shfl_xor(qA, off, 64);
            sB += __shfl_xor(sB, off, 64);
            qB += __shfl_xor(qB, off, 64);
        }
        if (lane == 0) {
            int base = (b * 340 + tile) * 8;
            part2[(base + 2 * wv) * 2]         = sA;
            part2[(base + 2 * wv) * 2 + 1]     = qA;
            part2[(base + 2 * wv + 1) * 2]     = sB;
            part2[(base + 2 * wv + 1) * 2 + 1] = qB;
        }
    } else {
        const float* a2p  = ab2 + (b * 4 + lvl) * 256;
        const float* be2p = a2p + 8192;
        float sj[4] = {0.f, 0.f, 0.f, 0.f};
#pragma unroll
        for (int mi = 0; mi < 4; ++mi) {
            int o4 = ob + mi * 16 + 4 * kg;
            floatx4 a2f  = *reinterpret_cast<const floatx4*>(a2p + o4);
            floatx4 be2f = *reinterpret_cast<const floatx4*>(be2p + o4);
            floatx4 w2f  = *reinterpret_cast<const floatx4*>(W2 + o4);
#pragma unroll
            for (int r = 0; r < 4; ++r) {
                float a2 = a2f[r], be2 = be2f[r], w2 = w2f[r], bb = b1f[mi][r];
#pragma unroll
                for (int ni = 0; ni < 4; ++ni) {
                    float h = fmaxf(fmaf(a2, acc[mi][ni][r] + bb, be2), 0.f);
                    sj[ni] = fmaf(w2, h, sj[ni]);
                }
            }
        }
        float* red = reinterpret_cast<float*>(Xs);
#pragma unroll
        for (int ni = 0; ni < 4; ++ni)
            red[(wv * 4 + kg) * 64 + ni * 16 + lr] = sj[ni];
        __syncthreads();
        if (t < 64) {
            float lg = b2[0];
#pragma unroll
            for (int m = 0; m < 16; ++m) lg += red[m * 64 + t];
            outF[800 + b * P_ + tile * 64 + t] = lg;
        }
    }
}

// ---------------- exact top-100 per batch: radix select + bitonic sort ----------------
// 1 block/batch, 1024 threads. Keys register-resident (22/thread).
__global__ __launch_bounds__(1024) void k_topk(const float* __restrict__ outF,
                                               float* __restrict__ outIds) {
    int b = blockIdx.x, t = threadIdx.x;
    __shared__ unsigned hist[256];
    __shared__ unsigned scan[256];
    __shared__ unsigned s_pref, s_K, s_iref, s_K2;
    __shared__ unsigned s_cnt;
    __shared__ unsigned long long cand[128];

    const float* src = outF + 800 + b * P_;
    unsigned key[22];
#pragma unroll
    for (int m = 0; m < 21; ++m) key[m] = fkey(src[t + m * 1024]);
    key[21] = (t < 256) ? fkey(src[t + 21504]) : 0u;
    bool has22 = (t < 256);

    if (t == 0) { s_K = 100; s_pref = 0; }

    // ---- 4 MSB-first radix passes on value keys ----
#pragma unroll
    for (int p = 0; p < 4; ++p) {
        int shift = 24 - 8 * p;
        for (int i = t; i < 256; i += 1024) hist[i] = 0;
        __syncthreads();
        unsigned pref = s_pref;
#pragma unroll
        for (int m = 0; m < 22; ++m) {
            if (m < 21 || has22) {
                unsigned u = key[m];
                if (p == 0 || (u >> (shift + 8)) == pref)
                    atomicAdd(&hist[(u >> shift) & 255], 1u);
            }
        }
        __syncthreads();
        if (t < 256) scan[t] = hist[t];
        __syncthreads();
        for (int off = 1; off < 256; off <<= 1) {            // suffix sum
            unsigned v = 0;
            if (t < 256 && t + off < 256) v = scan[t + off];
            __syncthreads();
            if (t < 256) scan[t] += v;
            __syncthreads();
        }
        unsigned K = s_K;
        if (t < 256) {
            unsigned above = (t == 255) ? 0u : scan[t + 1];
            if (scan[t] >= K && above < K) {
                s_pref = (s_pref << 8) | (unsigned)t;
                s_K = K - above;
            }
        }
        __syncthreads();
    }
    unsigned T = s_pref;      // exact key of 100th-largest
    if (t == 0) { s_K2 = s_K; s_iref = 0; }
    __syncthreads();

    // ---- 2 radix passes on index among ties (R-th smallest index) ----
#pragma unroll
    for (int p = 0; p < 2; ++p) {
        int shift = 8 - 8 * p;
        for (int i = t; i < 256; i += 1024) hist[i] = 0;
        __syncthreads();
        unsigned iref = s_iref;
#pragma unroll
        for (int m = 0; m < 22; ++m) {
            if (m < 21 || has22) {
                unsigned u = key[m];
                unsigned idx = (unsigned)(t + m * 1024);
                if (u == T && (p == 0 || (idx >> 8) == iref))
                    atomicAdd(&hist[(idx >> shift) & 255], 1u);
            }
        }
        __syncthreads();
        if (t < 256) scan[t] = hist[t];
        __syncthreads();
        for (int off = 1; off < 256; off <<= 1) {            // prefix sum
            unsigned v = 0;
            if (t < 256 && t >= off) v = scan[t - off];
            __syncthreads();
            if (t < 256) scan[t] += v;
            __syncthreads();
        }
        unsigned K2 = s_K2;
        if (t < 256) {
            unsigned below = (t == 0) ? 0u : scan[t - 1];
            if (scan[t] >= K2 && below < K2) {
                s_iref = (s_iref << 8) | (unsigned)t;
                s_K2 = K2 - below;
            }
        }
        __syncthreads();
    }
    unsigned Ti = s_iref;     // R-th smallest tie index

    // ---- compaction: exactly 100 selected ----
    if (t == 0) s_cnt = 0;
    if (t < 128) cand[t] = 0ull;
    __syncthreads();
#pragma unroll
    for (int m = 0; m < 22; ++m) {
        if (m < 21 || has22) {
            unsigned u = key[m];
            unsigned idx = (unsigned)(t + m * 1024);
            if (u > T || (u == T && idx <= Ti)) {
                unsigned p = atomicAdd(&s_cnt, 1u);
                if (p < 128)
                    cand[p] = ((unsigned long long)u << 32) | (unsigned long long)(0xFFFFFFFFu - idx);
            }
        }
    }
    __syncthreads();

    // ---- bitonic sort 128, descending (value desc, idx asc) ----
    for (unsigned k = 2; k <= 128; k <<= 1) {
        for (unsigned j = k >> 1; j > 0; j >>= 1) {
            if (t < 128) {
                unsigned i = t, ixj = i ^ j;
                if (ixj > i) {
                    unsigned long long a = cand[i], c = cand[ixj];
                    bool desc = ((i & k) == 0);
                    if ((a < c) == desc) { cand[i] = c; cand[ixj] = a; }
                }
            }
            __syncthreads();
        }
    }
    if (t < 100) {
        unsigned idx = 0xFFFFFFFFu - (unsigned)(cand[t] & 0xFFFFFFFFull);
        outIds[b * 100 + t] = (float)idx;
    }
}

extern "C" void kernel_launch(void* const* d_in, const int* in_sizes, int n_in,
                              void* d_out, int out_size, void* d_ws, size_t ws_size,
                              hipStream_t stream) {
    const float* x0  = (const float*)d_in[0];
    const float* x1  = (const float*)d_in[1];
    const float* x2  = (const float*)d_in[2];
    const float* x3  = (const float*)d_in[3];
    const float* g1s = (const float*)d_in[4];
    const float* g1b = (const float*)d_in[5];
    const float* W1  = (const float*)d_in[6];
    const float* b1  = (const float*)d_in[7];
    const float* g2s = (const float*)d_in[8];
    const float* g2b = (const float*)d_in[9];
    const float* W2  = (const float*)d_in[10];
    const float* b2  = (const float*)d_in[11];
    float* outF = (float*)d_out;
    float* ws = (float*)d_ws;

    // ws layout (floats)
    float*  ab1   = ws;                     // 16384
    float*  ab2   = ws + 16384;             // 16384
    float*  U     = ws + 32768;             // 43520 shared region (part1/part2)
    float*  part1 = U;
    float*  part2 = U;
    ushort* Whi   = (ushort*)(ws + 76288);  // 65536 ushorts
    ushort* Wlo   = (ushort*)(ws + 109056); // 65536 ushorts

    k_wsplit<<<dim3(256), dim3(256), 0, stream>>>(W1, Whi, Wlo);
    k_stats1<<<dim3(85, 8), dim3(256), 0, stream>>>(x0, x1, x2, x3, part1);
    k_finalize<<<dim3(1), dim3(256), 0, stream>>>(part1, 256, g1s, g1b, ab1);
    k_gemm<0><<<dim3(340, 8), dim3(256), 0, stream>>>(x0, x1, x2, x3, Whi, Wlo, ab1, b1,
                                                      part2, ab2, W2, b2, outF);
    k_finalize<<<dim3(1), dim3(256), 0, stream>>>(part2, 64, g2s, g2b, ab2);
    k_gemm<2><<<dim3(340, 8), dim3(256), 0, stream>>>(x0, x1, x2, x3, Whi, Wlo, ab1, b1,
                                                      part2, ab2, W2, b2, outF);
    k_topk<<<dim3(8), dim3(1024), 0, stream>>>(outF, outF);
}